// Round 10
// baseline (1137.831 us; speedup 1.0000x reference)
//
#include <hip/hip_runtime.h>

#define B_ 128
#define L_ 64
#define V_ 8192
#define E_ 128
#define H_ 128
#define G4_ 512
#define NROW (B_*L_)
#define HSTRIDE 136
#define AS 136
#define XS 264
#define YS 136
#define ZS 132

typedef unsigned short u16;
typedef __attribute__((ext_vector_type(8))) short bf16x8;
typedef __attribute__((ext_vector_type(4))) float f32x4;

__device__ __forceinline__ float sigm(float x){ return 1.f/(1.f + __expf(-x)); }
__device__ __forceinline__ float ftanh(float x){ float e = __expf(2.f*x); return 1.f - 2.f/(e + 1.f); }
__device__ __forceinline__ u16 f2bf(float f){
    union { unsigned int i; float f; } x; x.f = f;
    unsigned int r = x.i + 0x7fff + ((x.i >> 16) & 1);
    return (u16)(r >> 16);
}
// raw barrier: LDS-only sync, no vmcnt drain
#define LBAR() asm volatile("s_waitcnt lgkmcnt(0)\ns_barrier" ::: "memory")

__device__ __forceinline__ bf16x8 pack8(const float* p){
    const float4* q = (const float4*)p;
    float4 a = q[0], b = q[1];
    bf16x8 f;
    f[0]=(short)f2bf(a.x); f[1]=(short)f2bf(a.y); f[2]=(short)f2bf(a.z); f[3]=(short)f2bf(a.w);
    f[4]=(short)f2bf(b.x); f[5]=(short)f2bf(b.y); f[6]=(short)f2bf(b.z); f[7]=(short)f2bf(b.w);
    return f;
}

// ---------------------------------------------------------------- transpose W_visit [E,V] -> WT [V,E]
__global__ __launch_bounds__(256) void k_transpose_wv(const float* __restrict__ Wv, float* __restrict__ WT){
    __shared__ float tile[16][129];
    int v0 = blockIdx.x * 16;
    int t = threadIdx.x;
    #pragma unroll
    for(int i=0;i<8;i++){
        int idx = i*256 + t; int e = idx >> 4; int vv = idx & 15;
        tile[vv][e] = Wv[(size_t)e*V_ + v0 + vv];
    }
    __syncthreads();
    #pragma unroll
    for(int i=0;i<8;i++){
        int idx = i*256 + t; int vv = idx >> 7; int e = idx & 127;
        WT[(size_t)(v0+vv)*E_ + e] = tile[vv][e];
    }
}

// ---------------------------------------------------------------- v = (x @ Wv^T + bin_embed[delta]) * m
__global__ __launch_bounds__(256) void k_visit_embed(const float* __restrict__ px, const float* __restrict__ vmask,
                                                     const int* __restrict__ bins, const float* __restrict__ bemb,
                                                     const float* __restrict__ WT, float* __restrict__ v){
    __shared__ int idxs[512];
    __shared__ int cnt;
    __shared__ int dsh;
    __shared__ float msh;
    __shared__ float4 red[8][32];
    int row = blockIdx.x; int l = row & 63;
    int t = threadIdx.x;
    if(t==0){
        cnt = 0;
        float m = vmask[row];
        int d = 0;
        if(l > 0){ d = bins[row] - bins[row-1]; d = d < 0 ? 0 : (d > 513 ? 513 : d); }
        if(!(m > 0.f)) d = 0;
        dsh = d; msh = m;
    }
    __syncthreads();
    const uint4* xr4 = (const uint4*)(px + (size_t)row * V_);
    for(int i=t;i<2048;i+=256){
        uint4 u = xr4[i];
        unsigned int w[4] = {u.x,u.y,u.z,u.w};
        #pragma unroll
        for(int j=0;j<4;j++){
            if(w[j]){ int p = atomicAdd(&cnt,1); if(p<512) idxs[p] = i*4 + j; }
        }
    }
    __syncthreads();
    int n = cnt; if(n > 512) n = 512;
    int eq = t & 31, jg = t >> 5;
    float4 a4 = {0.f,0.f,0.f,0.f};
    for(int j=jg;j<n;j+=8){
        const float4* wr = (const float4*)(WT + (size_t)idxs[j]*E_);
        float4 wv = wr[eq];
        a4.x += wv.x; a4.y += wv.y; a4.z += wv.z; a4.w += wv.w;
    }
    red[jg][eq] = a4;
    __syncthreads();
    if(t < 32){
        float4 s = red[0][t];
        #pragma unroll
        for(int g=1;g<8;g++){
            float4 r = red[g][t];
            s.x += r.x; s.y += r.y; s.z += r.z; s.w += r.w;
        }
        const float4* bp = (const float4*)(bemb + dsh*E_);
        float4 bv = bp[t];
        float m = msh;
        float4 o;
        o.x = (s.x + bv.x)*m; o.y = (s.y + bv.y)*m; o.z = (s.z + bv.z)*m; o.w = (s.w + bv.w)*m;
        ((float4*)(v + (size_t)row*E_))[t] = o;
    }
}

// ---------------------------------------------------------------- xg = A @ W_ih^T + b_ih + b_hh (MFMA, fp32 out)
__global__ __launch_bounds__(256,2) void k_gemm_xg(const float* __restrict__ A, const float* __restrict__ Wih,
                                                   const float* __restrict__ bih, const float* __restrict__ bhh,
                                                   float* __restrict__ xg){
    __shared__ __align__(16) u16 abuf[16*AS];
    int t = threadIdx.x, wave = t >> 6, lane = t & 63, quad = lane >> 4, lc = lane & 15;
    int row0 = blockIdx.x * 16;
    #pragma unroll
    for(int i=0;i<8;i++){
        int flat = i*256 + t; int r = flat >> 7, e = flat & 127;
        abuf[r*AS + e] = f2bf(A[(size_t)(row0+r)*E_ + e]);
    }
    bf16x8 wfr[8][4]; float bb[8];
    #pragma unroll
    for(int nt=0;nt<8;nt++){
        int n = wave*128 + nt*16 + lc;
        bb[nt] = bih[n] + bhh[n];
        const float* wr = Wih + (size_t)n*E_ + quad*8;
        #pragma unroll
        for(int kt=0;kt<4;kt++) wfr[nt][kt] = pack8(wr + kt*32);
    }
    __syncthreads();
    f32x4 acc[8];
    #pragma unroll
    for(int nt=0;nt<8;nt++) acc[nt] = (f32x4){0.f,0.f,0.f,0.f};
    #pragma unroll
    for(int kt=0;kt<4;kt++){
        bf16x8 af = *(const bf16x8*)&abuf[lc*AS + kt*32 + quad*8];
        #pragma unroll
        for(int nt=0;nt<8;nt++)
            acc[nt] = __builtin_amdgcn_mfma_f32_16x16x32_bf16(af, wfr[nt][kt], acc[nt], 0,0,0);
    }
    #pragma unroll
    for(int nt=0;nt<8;nt++){
        int n = wave*128 + nt*16 + lc;
        #pragma unroll
        for(int r=0;r<4;r++)
            xg[(size_t)(row0 + quad*4 + r)*G4_ + n] = acc[nt][r] + bb[nt];
    }
}

// ---------------------------------------------------------------- LSTM: two interleaved 16-row chains per block
// 512 thr / 8 waves; wave owns 16 gate-cols (cw) for all 4 gates; weights shared by both chains.
// One LBAR per round serves one step of EACH chain; P's VALU overlaps Q's MFMA.
__device__ __forceinline__ void chain_step(int l, const float* pxg, float* hp_out, bool dohp,
        const u16* bufr, u16* bufw, const bf16x8 (&bf)[4][4], const bf16x8 (&wp)[4],
        float (&xgbuf)[4][4], float (&c4)[4], float (&lg4)[4],
        const int (&len4)[4], float wcv,
        const float* vmsh, int lc, int quad, int cw, int base){
    float xloc[4][4];
    #pragma unroll
    for(int gate=0;gate<4;gate++){
        #pragma unroll
        for(int r=0;r<4;r++) xloc[gate][r] = xgbuf[gate][r];
    }
    if(l+2 < 64){
        #pragma unroll
        for(int gate=0;gate<4;gate++){
            #pragma unroll
            for(int r=0;r<4;r++)
                xgbuf[gate][r] = pxg[(size_t)r*64*G4_ + (size_t)(l+2)*G4_ + gate*128];
        }
    }
    bf16x8 af[4];
    #pragma unroll
    for(int kt=0;kt<4;kt++)
        af[kt] = *(const bf16x8*)&bufr[lc*HSTRIDE + kt*32 + quad*8];
    f32x4 acc[4], acch;
    #pragma unroll
    for(int a=0;a<4;a++) acc[a] = (f32x4){0.f,0.f,0.f,0.f};
    acch = (f32x4){0.f,0.f,0.f,0.f};
    #pragma unroll
    for(int kt=0;kt<4;kt++){
        #pragma unroll
        for(int a=0;a<4;a++)
            acc[a] = __builtin_amdgcn_mfma_f32_16x16x32_bf16(af[kt], bf[a][kt], acc[a], 0,0,0);
        acch = __builtin_amdgcn_mfma_f32_16x16x32_bf16(af[kt], wp[kt], acch, 0,0,0);
    }
    #pragma unroll
    for(int r=0;r<4;r++){
        float m = vmsh[(quad*4+r)*64 + l];
        if(dohp){
            int grow = (base + quad*4 + r)*64 + l;
            hp_out[(size_t)grow*E_ + cw] = acch[r] * m;
        }
        float gi = acc[0][r] + xloc[0][r];
        float gf = acc[1][r] + xloc[1][r];
        float gg = acc[2][r] + xloc[2][r];
        float go = acc[3][r] + xloc[3][r];
        float c  = sigm(gf)*c4[r] + sigm(gi)*ftanh(gg);
        float h  = sigm(go)*ftanh(c);
        c4[r] = c;
        bufw[(quad*4+r)*HSTRIDE + cw] = f2bf(h);
        if(l == len4[r]-1) lg4[r] += h * wcv;
    }
    // NO barrier here — caller barriers once per round (both chains)
}

__global__ __launch_bounds__(512,1) void k_lstm_fused(const float* __restrict__ xg, const float* __restrict__ Whh,
        const float* __restrict__ Wproj, const float* __restrict__ Wcls, const float* __restrict__ bcls,
        const float* __restrict__ vmask, float* __restrict__ hp_out, float* __restrict__ logits_out){
    __shared__ u16 hbuf[2][2][16*HSTRIDE];     // [chain][parity]
    __shared__ float vmsh[32*64];
    __shared__ int lensh[32];
    __shared__ float lgsh[32][132];
    int t = threadIdx.x;
    int wave = t >> 6, lane = t & 63;
    int quad = lane >> 4, lc = lane & 15;
    int b0 = blockIdx.x * 32;
    bool dohp = (hp_out != nullptr);

    for(int i=t;i<2*16*HSTRIDE;i+=512){ hbuf[0][0][i>=16*HSTRIDE ? i-16*HSTRIDE : i] = 0; }
    // zero parity-0 of both chains (written rows overwrite every step; parity-1 fully written each odd step before read)
    for(int i=t;i<16*HSTRIDE;i+=512){ hbuf[0][0][i] = 0; hbuf[1][0][i] = 0; }
    for(int i=t;i<2048;i+=512) vmsh[i] = vmask[b0*64 + i];
    __syncthreads();
    if(t < 32){
        int s = 0;
        #pragma unroll
        for(int i=0;i<64;i++) s += (vmsh[t*64 + i] > 0.f) ? 1 : 0;
        lensh[t] = s < 1 ? 1 : s;
    }

    int cw = wave*16 + lc;
    bf16x8 bf[4][4];
    #pragma unroll
    for(int gate=0;gate<4;gate++){
        int n = gate*128 + cw;
        const float* wr = Whh + (size_t)n*H_ + quad*8;
        #pragma unroll
        for(int kt=0;kt<4;kt++) bf[gate][kt] = pack8(wr + kt*32);
    }
    bf16x8 wp[4];
    {
        const float* wr = Wproj + (size_t)cw*H_ + quad*8;
        #pragma unroll
        for(int kt=0;kt<4;kt++) wp[kt] = pack8(wr + kt*32);
    }
    float wcv = Wcls[cw];

    float c4P[4] = {0,0,0,0}, c4Q[4] = {0,0,0,0};
    float lgP[4] = {0,0,0,0}, lgQ[4] = {0,0,0,0};

    const float* pxgP = xg + ((size_t)(b0 + quad*4))*64*G4_ + cw;
    const float* pxgQ = xg + ((size_t)(b0 + 16 + quad*4))*64*G4_ + cw;

    // prefetch xg l=0 (E) and l=1 (O) for both chains
    float xPE[4][4], xPO[4][4], xQE[4][4], xQO[4][4];
    #pragma unroll
    for(int gate=0;gate<4;gate++){
        #pragma unroll
        for(int r=0;r<4;r++){
            xPE[gate][r] = pxgP[(size_t)r*64*G4_ + gate*128];
            xPO[gate][r] = pxgP[(size_t)r*64*G4_ + G4_ + gate*128];
            xQE[gate][r] = pxgQ[(size_t)r*64*G4_ + gate*128];
            xQO[gate][r] = pxgQ[(size_t)r*64*G4_ + G4_ + gate*128];
        }
    }
    __syncthreads();
    int lenP[4], lenQ[4];
    #pragma unroll
    for(int r=0;r<4;r++){ lenP[r] = lensh[quad*4 + r]; lenQ[r] = lensh[16 + quad*4 + r]; }

    for(int lb=0;lb<64;lb+=2){
        chain_step(lb,   pxgP, hp_out, dohp, hbuf[0][0], hbuf[0][1], bf, wp, xPE, c4P, lgP, lenP, wcv, vmsh,        lc, quad, cw, b0);
        chain_step(lb,   pxgQ, hp_out, dohp, hbuf[1][0], hbuf[1][1], bf, wp, xQE, c4Q, lgQ, lenQ, wcv, vmsh + 1024, lc, quad, cw, b0 + 16);
        LBAR();
        chain_step(lb+1, pxgP, hp_out, dohp, hbuf[0][1], hbuf[0][0], bf, wp, xPO, c4P, lgP, lenP, wcv, vmsh,        lc, quad, cw, b0);
        chain_step(lb+1, pxgQ, hp_out, dohp, hbuf[1][1], hbuf[1][0], bf, wp, xQO, c4Q, lgQ, lenQ, wcv, vmsh + 1024, lc, quad, cw, b0 + 16);
        LBAR();
    }
    #pragma unroll
    for(int r=0;r<4;r++){
        lgsh[quad*4 + r][cw] = lgP[r];
        lgsh[16 + quad*4 + r][cw] = lgQ[r];
    }
    __syncthreads();
    {
        int row = t >> 4, c16 = t & 15;
        float s = 0.f;
        #pragma unroll
        for(int j=0;j<8;j++) s += lgsh[row][c16 + j*16];
        s += __shfl_down(s, 8);
        s += __shfl_down(s, 4);
        s += __shfl_down(s, 2);
        s += __shfl_down(s, 1);
        if(c16 == 0) logits_out[b0 + row] = s + bcls[0];
    }
}

// ---------------------------------------------------------------- fused: diff_loss + reverse + xg2 GEMM (fp32 out)
__global__ __launch_bounds__(256,2) void k_drg(const float* __restrict__ v, const float* __restrict__ hp,
        const float* __restrict__ eps, const int* __restrict__ tdiff, const float* __restrict__ vmask,
        const float* __restrict__ z0, const float* __restrict__ noise, const float* __restrict__ temb,
        const float* __restrict__ Wf, const float* __restrict__ bfu,
        const float* __restrict__ We1, const float* __restrict__ be1,
        const float* __restrict__ We2, const float* __restrict__ be2,
        const float* __restrict__ Wih, const float* __restrict__ bih, const float* __restrict__ bhh,
        float* __restrict__ partial, float* __restrict__ xg2){
    __shared__ float zbuf[16*ZS], hpbuf[16*ZS];
    __shared__ __align__(16) u16 xbuf[16*XS];
    __shared__ __align__(16) u16 y1buf[16*YS];
    __shared__ float wfsh[512];
    __shared__ float ssh[16][2], hpd[16][2];
    __shared__ float mrow[16]; __shared__ int trow[16];
    __shared__ float sbeta[10], sabar[10];
    __shared__ float rb[4];
    int row0 = blockIdx.x * 16; int t = threadIdx.x;
    int wave = t >> 6, lane = t & 63, quad = lane >> 4, lc = lane & 15;

    if(t==0){
        float p = 1.f;
        for(int k=0;k<10;k++){ float b = 1e-4f + (0.02f - 1e-4f)*k/9.f; sbeta[k] = b; p *= (1.f - b); sabar[k] = p; }
    }
    if(t < 16){
        int row = row0 + t; float m = vmask[row];
        mrow[t] = m; trow[t] = (m > 0.f) ? tdiff[row >> 6] : 1;
    }
    for(int i=t;i<512;i+=256) wfsh[i] = Wf[i];
    float z0reg[8];
    #pragma unroll
    for(int i=0;i<8;i++){
        int flat = i*256 + t; int r = flat >> 7; int e = flat & 127;
        z0reg[i] = z0[(size_t)(row0+r)*E_ + e];
    }
    __syncthreads();
    #pragma unroll
    for(int i=0;i<8;i++){
        int flat = i*256 + t; int r = flat >> 7; int e = flat & 127; int row = row0 + r;
        float ab = sabar[trow[r]-1];
        zbuf[r*ZS + e] = (sqrtf(ab)*v[(size_t)row*E_ + e] + sqrtf(1.f - ab)*eps[(size_t)row*E_ + e]) * mrow[r];
        hpbuf[r*ZS + e] = hp[(size_t)row*E_ + e];
    }
    bf16x8 wf1[2][8], wf2[2][4];
    float be1v[2], be2v[2];
    #pragma unroll
    for(int nt=0;nt<2;nt++){
        int n = wave*32 + nt*16 + lc;
        be1v[nt] = be1[n]; be2v[nt] = be2[n];
        const float* w1 = We1 + (size_t)n*256 + quad*8;
        #pragma unroll
        for(int kt=0;kt<8;kt++) wf1[nt][kt] = pack8(w1 + kt*32);
        const float* w2 = We2 + (size_t)n*128 + quad*8;
        #pragma unroll
        for(int kt=0;kt<4;kt++) wf2[nt][kt] = pack8(w2 + kt*32);
    }
    __syncthreads();
    {
        int row = t >> 4, k = (t >> 3) & 1, sub = t & 7;
        float p = 0.f;
        #pragma unroll
        for(int i=0;i<16;i++)
            p += hpbuf[row*ZS + sub*16 + i] * wfsh[k*256 + 128 + sub*16 + i];
        p += __shfl_down(p,4); p += __shfl_down(p,2); p += __shfl_down(p,1);
        if(sub == 0) hpd[row][k] = p + bfu[k];
    }
    LBAR();

    for(int s=0;s<11;s++){
        int kk = 10 - (s - 1);
        float nzreg[2][4];
        if(s >= 1){
            #pragma unroll
            for(int nt=0;nt<2;nt++){
                #pragma unroll
                for(int r=0;r<4;r++)
                    nzreg[nt][r] = noise[((size_t)(s-1)*NROW + row0 + quad*4 + r)*E_ + wave*32 + nt*16 + lc];
            }
        }
        {
            int row = t >> 4, k = (t >> 3) & 1, sub = t & 7;
            float q = 0.f;
            #pragma unroll
            for(int i=0;i<16;i++)
                q += zbuf[row*ZS + sub*16 + i] * wfsh[k*256 + sub*16 + i];
            q += __shfl_down(q,4); q += __shfl_down(q,2); q += __shfl_down(q,1);
            if(sub == 0) ssh[row][k] = q + hpd[row][k];
        }
        LBAR();
        {
            int row = t >> 4, c0 = (t & 15) * 16;
            float s0 = ssh[row][0], s1 = ssh[row][1];
            float a0 = 1.f/(1.f + __expf(s1 - s0)), a1 = 1.f - a0;
            int tt = (s == 0) ? trow[row] : ((mrow[row] > 0.f) ? kk : 1);
            #pragma unroll
            for(int i=0;i<16;i++){
                int c = c0 + i;
                float val = (c < 128) ? (a0*zbuf[row*ZS + c] + a1*hpbuf[row*ZS + c])
                                      : temb[tt*E_ + (c - 128)];
                xbuf[row*XS + c] = f2bf(val);
            }
        }
        LBAR();
        f32x4 acc1[2];
        acc1[0] = (f32x4){0.f,0.f,0.f,0.f}; acc1[1] = (f32x4){0.f,0.f,0.f,0.f};
        #pragma unroll
        for(int kt=0;kt<8;kt++){
            bf16x8 af = *(const bf16x8*)&xbuf[lc*XS + kt*32 + quad*8];
            acc1[0] = __builtin_amdgcn_mfma_f32_16x16x32_bf16(af, wf1[0][kt], acc1[0], 0,0,0);
            acc1[1] = __builtin_amdgcn_mfma_f32_16x16x32_bf16(af, wf1[1][kt], acc1[1], 0,0,0);
        }
        #pragma unroll
        for(int nt=0;nt<2;nt++){
            #pragma unroll
            for(int r=0;r<4;r++)
                y1buf[(quad*4+r)*YS + wave*32 + nt*16 + lc] = f2bf(fmaxf(acc1[nt][r] + be1v[nt], 0.f));
        }
        LBAR();
        f32x4 acc2[2];
        acc2[0] = (f32x4){0.f,0.f,0.f,0.f}; acc2[1] = (f32x4){0.f,0.f,0.f,0.f};
        #pragma unroll
        for(int kt=0;kt<4;kt++){
            bf16x8 af = *(const bf16x8*)&y1buf[lc*YS + kt*32 + quad*8];
            acc2[0] = __builtin_amdgcn_mfma_f32_16x16x32_bf16(af, wf2[0][kt], acc2[0], 0,0,0);
            acc2[1] = __builtin_amdgcn_mfma_f32_16x16x32_bf16(af, wf2[1][kt], acc2[1], 0,0,0);
        }
        if(s == 0){
            float lp = 0.f;
            #pragma unroll
            for(int nt=0;nt<2;nt++){
                int n = wave*32 + nt*16 + lc;
                #pragma unroll
                for(int r=0;r<4;r++){
                    int m = quad*4 + r;
                    float d = (acc2[nt][r] + be2v[nt]) - eps[(size_t)(row0+m)*E_ + n];
                    lp += d*d*mrow[m];
                }
            }
            #pragma unroll
            for(int off=32;off;off>>=1) lp += __shfl_down(lp, off);
            if(lane == 0) rb[wave] = lp;
            LBAR();
            if(t == 0) partial[blockIdx.x] = rb[0]+rb[1]+rb[2]+rb[3];
            #pragma unroll
            for(int i=0;i<8;i++){
                int flat = i*256 + t; int r = flat >> 7; int e = flat & 127;
                zbuf[r*ZS + e] = z0reg[i];
            }
            LBAR();
        } else {
            float beta = sbeta[kk-1];
            float c1 = beta / sqrtf(1.f - sabar[kk-1]);
            float c2 = 1.f / sqrtf(1.f - beta);
            float sb = sqrtf(beta);
            #pragma unroll
            for(int nt=0;nt<2;nt++){
                int n = wave*32 + nt*16 + lc;
                #pragma unroll
                for(int r=0;r<4;r++){
                    int m = quad*4 + r;
                    float e = acc2[nt][r] + be2v[nt];
                    float z = zbuf[m*ZS + n];
                    float mean = (z - c1*e) * c2;
                    float znew = (kk > 1) ? (mean + sb*nzreg[nt][r]) : mean;
                    zbuf[m*ZS + n] = znew * mrow[m];
                }
            }
            LBAR();
        }
    }
    {
        int row = t >> 4, c0 = (t & 15) * 8;
        #pragma unroll
        for(int i=0;i<8;i++)
            xbuf[row*XS + c0 + i] = f2bf(zbuf[row*ZS + c0 + i]);
    }
    bf16x8 wg[8][4]; float bb[8];
    #pragma unroll
    for(int nt=0;nt<8;nt++){
        int n = wave*128 + nt*16 + lc;
        bb[nt] = bih[n] + bhh[n];
        const float* wr = Wih + (size_t)n*E_ + quad*8;
        #pragma unroll
        for(int kt=0;kt<4;kt++) wg[nt][kt] = pack8(wr + kt*32);
    }
    LBAR();
    f32x4 ac[8];
    #pragma unroll
    for(int nt=0;nt<8;nt++) ac[nt] = (f32x4){0.f,0.f,0.f,0.f};
    #pragma unroll
    for(int kt=0;kt<4;kt++){
        bf16x8 af = *(const bf16x8*)&xbuf[lc*XS + kt*32 + quad*8];
        #pragma unroll
        for(int nt=0;nt<8;nt++)
            ac[nt] = __builtin_amdgcn_mfma_f32_16x16x32_bf16(af, wg[nt][kt], ac[nt], 0,0,0);
    }
    #pragma unroll
    for(int nt=0;nt<8;nt++){
        int n = wave*128 + nt*16 + lc;
        #pragma unroll
        for(int r=0;r<4;r++)
            xg2[(size_t)(row0 + quad*4 + r)*G4_ + n] = ac[nt][r] + bb[nt];
    }
}

// ---------------------------------------------------------------- loss finalize
__global__ void k_finalize(const float* __restrict__ partial, const float* __restrict__ vmask, float* __restrict__ out){
    __shared__ float rb[4], rl[4];
    int t = threadIdx.x;
    float s = 0.f;
    for(int i=t;i<NROW;i+=256) s += vmask[i];
    float ls = 0.f;
    for(int i=t;i<512;i+=256) ls += partial[i];
    #pragma unroll
    for(int off=32;off;off>>=1){ s += __shfl_down(s, off); ls += __shfl_down(ls, off); }
    if((t & 63) == 0){ rb[t >> 6] = s; rl[t >> 6] = ls; }
    __syncthreads();
    if(t == 0){
        float denom = rb[0]+rb[1]+rb[2]+rb[3];
        if(denom < 1.f) denom = 1.f;
        out[256] = (rl[0]+rl[1]+rl[2]+rl[3]) / denom;
    }
}

extern "C" void kernel_launch(void* const* d_in, const int* in_sizes, int n_in,
                              void* d_out, int out_size, void* d_ws, size_t ws_size,
                              hipStream_t stream){
    const float* px    = (const float*)d_in[0];
    const float* vmask = (const float*)d_in[1];
    const int*   bins  = (const int*)d_in[2];
    const int*   tdiff = (const int*)d_in[3];
    const float* eps   = (const float*)d_in[4];
    const float* z0    = (const float*)d_in[5];
    const float* noise = (const float*)d_in[6];
    const float* Wv    = (const float*)d_in[7];
    const float* bemb  = (const float*)d_in[8];
    const float* Wih   = (const float*)d_in[9];
    const float* Whh   = (const float*)d_in[10];
    const float* bih   = (const float*)d_in[11];
    const float* bhh   = (const float*)d_in[12];
    const float* Wcls  = (const float*)d_in[13];
    const float* bcls  = (const float*)d_in[14];
    const float* Wproj = (const float*)d_in[15];
    const float* temb  = (const float*)d_in[16];
    const float* Wf    = (const float*)d_in[17];
    const float* bfu   = (const float*)d_in[18];
    const float* We1   = (const float*)d_in[19];
    const float* be1   = (const float*)d_in[20];
    const float* We2   = (const float*)d_in[21];
    const float* be2   = (const float*)d_in[22];
    float* out = (float*)d_out;

    float* ws      = (float*)d_ws;
    float* WT      = ws;                 // 1,048,576
    float* v       = ws + 1048576;       // 1,048,576
    float* xg      = ws + 2097152;       // 4,194,304
    float* hp      = ws + 6291456;       // 1,048,576
    float* partial = ws + 7340032;       // 512

    hipLaunchKernelGGL(k_transpose_wv, dim3(V_/16), dim3(256), 0, stream, Wv, WT);
    hipLaunchKernelGGL(k_visit_embed, dim3(NROW), dim3(256), 0, stream, px, vmask, bins, bemb, WT, v);
    hipLaunchKernelGGL(k_gemm_xg, dim3(NROW/16), dim3(256), 0, stream, v, Wih, bih, bhh, xg);
    hipLaunchKernelGGL(k_lstm_fused, dim3(B_/32), dim3(512), 0, stream,
                       xg, Whh, Wproj, Wcls, bcls, vmask, hp, out);
    hipLaunchKernelGGL(k_drg, dim3(NROW/16), dim3(256), 0, stream,
                       v, hp, eps, tdiff, vmask, z0, noise, temb, Wf, bfu,
                       We1, be1, We2, be2, Wih, bih, bhh, partial, xg);
    hipLaunchKernelGGL(k_lstm_fused, dim3(B_/32), dim3(512), 0, stream,
                       xg, Whh, Wproj, Wcls, bcls, vmask, (float*)nullptr, out + 128);
    hipLaunchKernelGGL(k_finalize, dim3(1), dim3(256), 0, stream, partial, vmask, out);
}

// Round 11
// 815.571 us; speedup vs baseline: 1.3951x; 1.3951x over previous
//
#include <hip/hip_runtime.h>

#define B_ 128
#define L_ 64
#define V_ 8192
#define E_ 128
#define H_ 128
#define G4_ 512
#define NROW (B_*L_)
#define HSTRIDE 136
#define AS 136
#define XS 264
#define YS 136
#define ZS 132

typedef unsigned short u16;
typedef __attribute__((ext_vector_type(8))) short bf16x8;
typedef __attribute__((ext_vector_type(4))) float f32x4;

__device__ __forceinline__ float sigm(float x){ return 1.f/(1.f + __expf(-x)); }
__device__ __forceinline__ float ftanh(float x){ float e = __expf(2.f*x); return 1.f - 2.f/(e + 1.f); }
__device__ __forceinline__ u16 f2bf(float f){
    union { unsigned int i; float f; } x; x.f = f;
    unsigned int r = x.i + 0x7fff + ((x.i >> 16) & 1);
    return (u16)(r >> 16);
}
// raw barrier: LDS-only sync, no vmcnt drain (global loads/stores stay in flight)
#define LBAR() asm volatile("s_waitcnt lgkmcnt(0)\ns_barrier" ::: "memory")

__device__ __forceinline__ bf16x8 pack8(const float* p){
    const float4* q = (const float4*)p;
    float4 a = q[0], b = q[1];
    bf16x8 f;
    f[0]=(short)f2bf(a.x); f[1]=(short)f2bf(a.y); f[2]=(short)f2bf(a.z); f[3]=(short)f2bf(a.w);
    f[4]=(short)f2bf(b.x); f[5]=(short)f2bf(b.y); f[6]=(short)f2bf(b.z); f[7]=(short)f2bf(b.w);
    return f;
}

// ---------------------------------------------------------------- transpose W_visit [E,V] -> WT [V,E]
__global__ __launch_bounds__(256) void k_transpose_wv(const float* __restrict__ Wv, float* __restrict__ WT){
    __shared__ float tile[16][129];
    int v0 = blockIdx.x * 16;
    int t = threadIdx.x;
    #pragma unroll
    for(int i=0;i<8;i++){
        int idx = i*256 + t; int e = idx >> 4; int vv = idx & 15;
        tile[vv][e] = Wv[(size_t)e*V_ + v0 + vv];
    }
    __syncthreads();
    #pragma unroll
    for(int i=0;i<8;i++){
        int idx = i*256 + t; int vv = idx >> 7; int e = idx & 127;
        WT[(size_t)(v0+vv)*E_ + e] = tile[vv][e];
    }
}

// ---------------------------------------------------------------- v = (x @ Wv^T + bin_embed[delta]) * m
__global__ __launch_bounds__(256) void k_visit_embed(const float* __restrict__ px, const float* __restrict__ vmask,
                                                     const int* __restrict__ bins, const float* __restrict__ bemb,
                                                     const float* __restrict__ WT, float* __restrict__ v){
    __shared__ int idxs[512];
    __shared__ int cnt;
    __shared__ int dsh;
    __shared__ float msh;
    __shared__ float4 red[8][32];
    int row = blockIdx.x; int l = row & 63;
    int t = threadIdx.x;
    if(t==0){
        cnt = 0;
        float m = vmask[row];
        int d = 0;
        if(l > 0){ d = bins[row] - bins[row-1]; d = d < 0 ? 0 : (d > 513 ? 513 : d); }
        if(!(m > 0.f)) d = 0;
        dsh = d; msh = m;
    }
    __syncthreads();
    const uint4* xr4 = (const uint4*)(px + (size_t)row * V_);
    for(int i=t;i<2048;i+=256){
        uint4 u = xr4[i];
        unsigned int w[4] = {u.x,u.y,u.z,u.w};
        #pragma unroll
        for(int j=0;j<4;j++){
            if(w[j]){ int p = atomicAdd(&cnt,1); if(p<512) idxs[p] = i*4 + j; }
        }
    }
    __syncthreads();
    int n = cnt; if(n > 512) n = 512;
    int eq = t & 31, jg = t >> 5;
    float4 a4 = {0.f,0.f,0.f,0.f};
    for(int j=jg;j<n;j+=8){
        const float4* wr = (const float4*)(WT + (size_t)idxs[j]*E_);
        float4 wv = wr[eq];
        a4.x += wv.x; a4.y += wv.y; a4.z += wv.z; a4.w += wv.w;
    }
    red[jg][eq] = a4;
    __syncthreads();
    if(t < 32){
        float4 s = red[0][t];
        #pragma unroll
        for(int g=1;g<8;g++){
            float4 r = red[g][t];
            s.x += r.x; s.y += r.y; s.z += r.z; s.w += r.w;
        }
        const float4* bp = (const float4*)(bemb + dsh*E_);
        float4 bv = bp[t];
        float m = msh;
        float4 o;
        o.x = (s.x + bv.x)*m; o.y = (s.y + bv.y)*m; o.z = (s.z + bv.z)*m; o.w = (s.w + bv.w)*m;
        ((float4*)(v + (size_t)row*E_))[t] = o;
    }
}

// ---------------------------------------------------------------- xg = A @ W_ih^T + b_ih + b_hh (MFMA, pass 1 from v)
__global__ __launch_bounds__(256,2) void k_gemm_xg(const float* __restrict__ A, const float* __restrict__ Wih,
                                                   const float* __restrict__ bih, const float* __restrict__ bhh,
                                                   float* __restrict__ xg){
    __shared__ __align__(16) u16 abuf[16*AS];
    int t = threadIdx.x, wave = t >> 6, lane = t & 63, quad = lane >> 4, lc = lane & 15;
    int row0 = blockIdx.x * 16;
    #pragma unroll
    for(int i=0;i<8;i++){
        int flat = i*256 + t; int r = flat >> 7, e = flat & 127;
        abuf[r*AS + e] = f2bf(A[(size_t)(row0+r)*E_ + e]);
    }
    bf16x8 wfr[8][4]; float bb[8];
    #pragma unroll
    for(int nt=0;nt<8;nt++){
        int n = wave*128 + nt*16 + lc;
        bb[nt] = bih[n] + bhh[n];
        const float* wr = Wih + (size_t)n*E_ + quad*8;
        #pragma unroll
        for(int kt=0;kt<4;kt++) wfr[nt][kt] = pack8(wr + kt*32);
    }
    __syncthreads();
    f32x4 acc[8];
    #pragma unroll
    for(int nt=0;nt<8;nt++) acc[nt] = (f32x4){0.f,0.f,0.f,0.f};
    #pragma unroll
    for(int kt=0;kt<4;kt++){
        bf16x8 af = *(const bf16x8*)&abuf[lc*AS + kt*32 + quad*8];
        #pragma unroll
        for(int nt=0;nt<8;nt++)
            acc[nt] = __builtin_amdgcn_mfma_f32_16x16x32_bf16(af, wfr[nt][kt], acc[nt], 0,0,0);
    }
    #pragma unroll
    for(int nt=0;nt<8;nt++){
        int n = wave*128 + nt*16 + lc;
        #pragma unroll
        for(int r=0;r<4;r++)
            xg[(size_t)(row0 + quad*4 + r)*G4_ + n] = acc[nt][r] + bb[nt];
    }
}

// ---------------------------------------------------------------- LSTM fused: recurrence + hp (pass1) + logits
__device__ __forceinline__ void lstm_step(int l, const float* pxg, float* hp_out, bool dohp,
        const u16* bufr, u16* bufw, const bf16x8 (&bf)[4][4], const bf16x8 (&wp)[4],
        float (&xcur)[4][4], float (&xnxt)[4][4], float (&c4)[4], float (&lg4)[4],
        const int (&len4)[4], float wcv,
        const float* vmsh, int lc, int quad, int wave, int b0){
    // prefetch next step's xg first (longest latency)
    if(l+1 < 64){
        #pragma unroll
        for(int gate=0;gate<4;gate++){
            #pragma unroll
            for(int r=0;r<4;r++)
                xnxt[gate][r] = pxg[(size_t)r*64*G4_ + (size_t)(l+1)*G4_ + gate*128];
        }
    }
    bf16x8 af[4];
    #pragma unroll
    for(int kt=0;kt<4;kt++)
        af[kt] = *(const bf16x8*)&bufr[lc*HSTRIDE + kt*32 + quad*8];
    f32x4 acc[4], acch;
    #pragma unroll
    for(int a=0;a<4;a++) acc[a] = (f32x4){0.f,0.f,0.f,0.f};
    acch = (f32x4){0.f,0.f,0.f,0.f};
    #pragma unroll
    for(int kt=0;kt<4;kt++){
        #pragma unroll
        for(int a=0;a<4;a++)
            acc[a] = __builtin_amdgcn_mfma_f32_16x16x32_bf16(af[kt], bf[a][kt], acc[a], 0,0,0);
        acch = __builtin_amdgcn_mfma_f32_16x16x32_bf16(af[kt], wp[kt], acch, 0,0,0);
    }
    if(dohp){
        // hp[b, l] = h_{l-1} @ Wproj^T * m[b,l]  (af IS h_{l-1}; af=0 at l=0 -> hp=0)
        #pragma unroll
        for(int r=0;r<4;r++){
            float m = vmsh[(quad*4+r)*64 + l];
            int grow = (b0 + quad*4 + r)*64 + l;
            hp_out[(size_t)grow*E_ + wave*16 + lc] = acch[r] * m;
        }
    }
    #pragma unroll
    for(int r=0;r<4;r++){
        float gi = acc[0][r] + xcur[0][r];
        float gf = acc[1][r] + xcur[1][r];
        float gg = acc[2][r] + xcur[2][r];
        float go = acc[3][r] + xcur[3][r];
        float c  = sigm(gf)*c4[r] + sigm(gi)*ftanh(gg);
        float h  = sigm(go)*ftanh(c);
        c4[r] = c;
        bufw[(quad*4+r)*HSTRIDE + wave*16 + lc] = f2bf(h);
        if(l == len4[r]-1) lg4[r] += h * wcv;
    }
    LBAR();
}

__global__ __launch_bounds__(512,2) void k_lstm_fused(const float* __restrict__ xg, const float* __restrict__ Whh,
        const float* __restrict__ Wproj, const float* __restrict__ Wcls, const float* __restrict__ bcls,
        const float* __restrict__ vmask, float* __restrict__ hp_out, float* __restrict__ logits_out){
    __shared__ u16 hbuf[2][16*HSTRIDE];
    __shared__ float vmsh[16*64];
    __shared__ int lensh[16];
    __shared__ float lgsh[16][132];
    int t = threadIdx.x;
    int wave = t >> 6, lane = t & 63;
    int quad = lane >> 4, lc = lane & 15;
    int b0 = blockIdx.x * 16;
    bool dohp = (hp_out != nullptr);

    for(int i=t;i<16*HSTRIDE;i+=512) hbuf[0][i] = 0;
    for(int i=t;i<1024;i+=512) vmsh[i] = vmask[b0*64 + i];
    __syncthreads();
    if(t < 16){
        int s = 0;
        #pragma unroll
        for(int i=0;i<64;i++) s += (vmsh[t*64 + i] > 0.f) ? 1 : 0;
        lensh[t] = s < 1 ? 1 : s;
    }

    int cw = wave*16 + lc;
    bf16x8 bf[4][4];
    #pragma unroll
    for(int gate=0;gate<4;gate++){
        int n = gate*128 + cw;
        const float* wr = Whh + (size_t)n*H_ + quad*8;
        #pragma unroll
        for(int kt=0;kt<4;kt++) bf[gate][kt] = pack8(wr + kt*32);
    }
    bf16x8 wp[4];
    {
        const float* wr = Wproj + (size_t)cw*H_ + quad*8;
        #pragma unroll
        for(int kt=0;kt<4;kt++) wp[kt] = pack8(wr + kt*32);
    }
    float wcv = Wcls[cw];

    float c4[4] = {0.f,0.f,0.f,0.f};
    float lg4[4] = {0.f,0.f,0.f,0.f};

    const float* pxg = xg + ((size_t)(b0 + quad*4))*64*G4_ + cw;

    // prefetch xg for l=0
    float xgv0[4][4], xgv1[4][4];
    #pragma unroll
    for(int gate=0;gate<4;gate++){
        #pragma unroll
        for(int r=0;r<4;r++)
            xgv0[gate][r] = pxg[(size_t)r*64*G4_ + gate*128];
    }
    __syncthreads();
    int len4[4];
    #pragma unroll
    for(int r=0;r<4;r++) len4[r] = lensh[quad*4 + r];

    for(int lb=0;lb<64;lb+=2){
        lstm_step(lb,   pxg, hp_out, dohp, hbuf[0], hbuf[1], bf, wp, xgv0, xgv1, c4, lg4, len4, wcv, vmsh, lc, quad, wave, b0);
        lstm_step(lb+1, pxg, hp_out, dohp, hbuf[1], hbuf[0], bf, wp, xgv1, xgv0, c4, lg4, len4, wcv, vmsh, lc, quad, wave, b0);
    }
    #pragma unroll
    for(int r=0;r<4;r++) lgsh[quad*4+r][cw] = lg4[r];
    __syncthreads();
    {
        int row = t >> 5, l32 = t & 31;
        float s = lgsh[row][l32] + lgsh[row][l32+32] + lgsh[row][l32+64] + lgsh[row][l32+96];
        s += __shfl_down(s, 16, 32);
        s += __shfl_down(s, 8, 32);
        s += __shfl_down(s, 4, 32);
        s += __shfl_down(s, 2, 32);
        s += __shfl_down(s, 1, 32);
        if(l32 == 0) logits_out[b0 + row] = s + bcls[0];
    }
}

// ---------------------------------------------------------------- fused: diff_loss + reverse diffusion + xg2 GEMM
__global__ __launch_bounds__(256,2) void k_drg(const float* __restrict__ v, const float* __restrict__ hp,
        const float* __restrict__ eps, const int* __restrict__ tdiff, const float* __restrict__ vmask,
        const float* __restrict__ z0, const float* __restrict__ noise, const float* __restrict__ temb,
        const float* __restrict__ Wf, const float* __restrict__ bfu,
        const float* __restrict__ We1, const float* __restrict__ be1,
        const float* __restrict__ We2, const float* __restrict__ be2,
        const float* __restrict__ Wih, const float* __restrict__ bih, const float* __restrict__ bhh,
        float* __restrict__ partial, float* __restrict__ xg2){
    __shared__ float zbuf[16*ZS], hpbuf[16*ZS];
    __shared__ __align__(16) u16 xbuf[16*XS];
    __shared__ __align__(16) u16 y1buf[16*YS];
    __shared__ float wfsh[512];
    __shared__ float ssh[16][2], hpd[16][2];
    __shared__ float mrow[16]; __shared__ int trow[16];
    __shared__ float sbeta[10], sabar[10];
    __shared__ float rb[4];
    int row0 = blockIdx.x * 16; int t = threadIdx.x;
    int wave = t >> 6, lane = t & 63, quad = lane >> 4, lc = lane & 15;

    if(t==0){
        float p = 1.f;
        for(int k=0;k<10;k++){ float b = 1e-4f + (0.02f - 1e-4f)*k/9.f; sbeta[k] = b; p *= (1.f - b); sabar[k] = p; }
    }
    if(t < 16){
        int row = row0 + t; float m = vmask[row];
        mrow[t] = m; trow[t] = (m > 0.f) ? tdiff[row >> 6] : 1;
    }
    for(int i=t;i<512;i+=256) wfsh[i] = Wf[i];
    __syncthreads();
    // z_t (diffusion-loss forward sample) and hp into LDS
    #pragma unroll
    for(int i=0;i<8;i++){
        int flat = i*256 + t; int r = flat >> 7; int e = flat & 127; int row = row0 + r;
        float ab = sabar[trow[r]-1];
        zbuf[r*ZS + e] = (sqrtf(ab)*v[(size_t)row*E_ + e] + sqrtf(1.f - ab)*eps[(size_t)row*E_ + e]) * mrow[r];
        hpbuf[r*ZS + e] = hp[(size_t)row*E_ + e];
    }
    bf16x8 wf1[2][8], wf2[2][4];
    float be1v[2], be2v[2];
    #pragma unroll
    for(int nt=0;nt<2;nt++){
        int n = wave*32 + nt*16 + lc;
        be1v[nt] = be1[n]; be2v[nt] = be2[n];
        const float* w1 = We1 + (size_t)n*256 + quad*8;
        #pragma unroll
        for(int kt=0;kt<8;kt++) wf1[nt][kt] = pack8(w1 + kt*32);
        const float* w2 = We2 + (size_t)n*128 + quad*8;
        #pragma unroll
        for(int kt=0;kt<4;kt++) wf2[nt][kt] = pack8(w2 + kt*32);
    }
    __syncthreads();
    // hp·Wf[:,128:256]+bfu (reused by both diff and all 10 reverse steps)
    {
        int row = t >> 4, k = (t >> 3) & 1, sub = t & 7;
        float p = 0.f;
        #pragma unroll
        for(int i=0;i<16;i++)
            p += hpbuf[row*ZS + sub*16 + i] * wfsh[k*256 + 128 + sub*16 + i];
        p += __shfl_down(p,4); p += __shfl_down(p,2); p += __shfl_down(p,1);
        if(sub == 0) hpd[row][k] = p + bfu[k];
    }
    __syncthreads();

    // ---------- 11 fuse_eps evaluations: s=0 -> diff loss on z_t; s=1..10 -> reverse steps
    for(int s=0;s<11;s++){
        int kk = 10 - (s - 1);          // reverse step index for s>=1
        {
            int row = t >> 4, k = (t >> 3) & 1, sub = t & 7;
            float q = 0.f;
            #pragma unroll
            for(int i=0;i<16;i++)
                q += zbuf[row*ZS + sub*16 + i] * wfsh[k*256 + sub*16 + i];
            q += __shfl_down(q,4); q += __shfl_down(q,2); q += __shfl_down(q,1);
            if(sub == 0) ssh[row][k] = q + hpd[row][k];
        }
        __syncthreads();
        {
            int row = t >> 4, c0 = (t & 15) * 16;
            float s0 = ssh[row][0], s1 = ssh[row][1];
            float a0 = 1.f/(1.f + __expf(s1 - s0)), a1 = 1.f - a0;
            int tt = (s == 0) ? trow[row] : ((mrow[row] > 0.f) ? kk : 1);
            #pragma unroll
            for(int i=0;i<16;i++){
                int c = c0 + i;
                float val = (c < 128) ? (a0*zbuf[row*ZS + c] + a1*hpbuf[row*ZS + c])
                                      : temb[tt*E_ + (c - 128)];
                xbuf[row*XS + c] = f2bf(val);
            }
        }
        __syncthreads();
        f32x4 acc1[2];
        acc1[0] = (f32x4){0.f,0.f,0.f,0.f}; acc1[1] = (f32x4){0.f,0.f,0.f,0.f};
        #pragma unroll
        for(int kt=0;kt<8;kt++){
            bf16x8 af = *(const bf16x8*)&xbuf[lc*XS + kt*32 + quad*8];
            acc1[0] = __builtin_amdgcn_mfma_f32_16x16x32_bf16(af, wf1[0][kt], acc1[0], 0,0,0);
            acc1[1] = __builtin_amdgcn_mfma_f32_16x16x32_bf16(af, wf1[1][kt], acc1[1], 0,0,0);
        }
        #pragma unroll
        for(int nt=0;nt<2;nt++){
            #pragma unroll
            for(int r=0;r<4;r++)
                y1buf[(quad*4+r)*YS + wave*32 + nt*16 + lc] = f2bf(fmaxf(acc1[nt][r] + be1v[nt], 0.f));
        }
        __syncthreads();
        f32x4 acc2[2];
        acc2[0] = (f32x4){0.f,0.f,0.f,0.f}; acc2[1] = (f32x4){0.f,0.f,0.f,0.f};
        #pragma unroll
        for(int kt=0;kt<4;kt++){
            bf16x8 af = *(const bf16x8*)&y1buf[lc*YS + kt*32 + quad*8];
            acc2[0] = __builtin_amdgcn_mfma_f32_16x16x32_bf16(af, wf2[0][kt], acc2[0], 0,0,0);
            acc2[1] = __builtin_amdgcn_mfma_f32_16x16x32_bf16(af, wf2[1][kt], acc2[1], 0,0,0);
        }
        if(s == 0){
            // diffusion loss partial; then load z0 for the reverse chain
            float lp = 0.f;
            #pragma unroll
            for(int nt=0;nt<2;nt++){
                int n = wave*32 + nt*16 + lc;
                #pragma unroll
                for(int r=0;r<4;r++){
                    int m = quad*4 + r;
                    float d = (acc2[nt][r] + be2v[nt]) - eps[(size_t)(row0+m)*E_ + n];
                    lp += d*d*mrow[m];
                }
            }
            #pragma unroll
            for(int off=32;off;off>>=1) lp += __shfl_down(lp, off);
            if(lane == 0) rb[wave] = lp;
            __syncthreads();
            if(t == 0) partial[blockIdx.x] = rb[0]+rb[1]+rb[2]+rb[3];
            #pragma unroll
            for(int i=0;i<8;i++){
                int flat = i*256 + t; int r = flat >> 7; int e = flat & 127;
                zbuf[r*ZS + e] = z0[(size_t)(row0+r)*E_ + e];
            }
            __syncthreads();
        } else {
            float beta = sbeta[kk-1];
            float c1 = beta / sqrtf(1.f - sabar[kk-1]);
            float c2 = 1.f / sqrtf(1.f - beta);
            float sb = sqrtf(beta);
            #pragma unroll
            for(int nt=0;nt<2;nt++){
                int n = wave*32 + nt*16 + lc;
                #pragma unroll
                for(int r=0;r<4;r++){
                    int m = quad*4 + r;
                    float e = acc2[nt][r] + be2v[nt];
                    float z = zbuf[m*ZS + n];
                    float mean = (z - c1*e) * c2;
                    float nz = noise[((size_t)(s-1)*NROW + row0 + m)*E_ + n];
                    float znew = (kk > 1) ? (mean + sb*nz) : mean;
                    zbuf[m*ZS + n] = znew * mrow[m];
                }
            }
            __syncthreads();
        }
    }
    // ---------- xg2 = v_syn @ Wih^T + bih + bhh (v_syn = final zbuf)
    {
        int row = t >> 4, c0 = (t & 15) * 8;
        #pragma unroll
        for(int i=0;i<8;i++)
            xbuf[row*XS + c0 + i] = f2bf(zbuf[row*ZS + c0 + i]);
    }
    __syncthreads();
    bf16x8 wg[8][4]; float bb[8];
    #pragma unroll
    for(int nt=0;nt<8;nt++){
        int n = wave*128 + nt*16 + lc;
        bb[nt] = bih[n] + bhh[n];
        const float* wr = Wih + (size_t)n*E_ + quad*8;
        #pragma unroll
        for(int kt=0;kt<4;kt++) wg[nt][kt] = pack8(wr + kt*32);
    }
    f32x4 ac[8];
    #pragma unroll
    for(int nt=0;nt<8;nt++) ac[nt] = (f32x4){0.f,0.f,0.f,0.f};
    #pragma unroll
    for(int kt=0;kt<4;kt++){
        bf16x8 af = *(const bf16x8*)&xbuf[lc*XS + kt*32 + quad*8];
        #pragma unroll
        for(int nt=0;nt<8;nt++)
            ac[nt] = __builtin_amdgcn_mfma_f32_16x16x32_bf16(af, wg[nt][kt], ac[nt], 0,0,0);
    }
    #pragma unroll
    for(int nt=0;nt<8;nt++){
        int n = wave*128 + nt*16 + lc;
        #pragma unroll
        for(int r=0;r<4;r++)
            xg2[(size_t)(row0 + quad*4 + r)*G4_ + n] = ac[nt][r] + bb[nt];
    }
}

// ---------------------------------------------------------------- loss finalize (sums 512 partials + mask)
__global__ void k_finalize(const float* __restrict__ partial, const float* __restrict__ vmask, float* __restrict__ out){
    __shared__ float rb[4], rl[4];
    int t = threadIdx.x;
    float s = 0.f;
    for(int i=t;i<NROW;i+=256) s += vmask[i];
    float ls = 0.f;
    for(int i=t;i<512;i+=256) ls += partial[i];
    #pragma unroll
    for(int off=32;off;off>>=1){ s += __shfl_down(s, off); ls += __shfl_down(ls, off); }
    if((t & 63) == 0){ rb[t >> 6] = s; rl[t >> 6] = ls; }
    __syncthreads();
    if(t == 0){
        float denom = rb[0]+rb[1]+rb[2]+rb[3];
        if(denom < 1.f) denom = 1.f;
        out[256] = (rl[0]+rl[1]+rl[2]+rl[3]) / denom;
    }
}

extern "C" void kernel_launch(void* const* d_in, const int* in_sizes, int n_in,
                              void* d_out, int out_size, void* d_ws, size_t ws_size,
                              hipStream_t stream){
    const float* px    = (const float*)d_in[0];
    const float* vmask = (const float*)d_in[1];
    const int*   bins  = (const int*)d_in[2];
    const int*   tdiff = (const int*)d_in[3];
    const float* eps   = (const float*)d_in[4];
    const float* z0    = (const float*)d_in[5];
    const float* noise = (const float*)d_in[6];
    const float* Wv    = (const float*)d_in[7];
    const float* bemb  = (const float*)d_in[8];
    const float* Wih   = (const float*)d_in[9];
    const float* Whh   = (const float*)d_in[10];
    const float* bih   = (const float*)d_in[11];
    const float* bhh   = (const float*)d_in[12];
    const float* Wcls  = (const float*)d_in[13];
    const float* bcls  = (const float*)d_in[14];
    const float* Wproj = (const float*)d_in[15];
    const float* temb  = (const float*)d_in[16];
    const float* Wf    = (const float*)d_in[17];
    const float* bfu   = (const float*)d_in[18];
    const float* We1   = (const float*)d_in[19];
    const float* be1   = (const float*)d_in[20];
    const float* We2   = (const float*)d_in[21];
    const float* be2   = (const float*)d_in[22];
    float* out = (float*)d_out;

    float* ws      = (float*)d_ws;
    float* WT      = ws;                 // 1,048,576
    float* v       = ws + 1048576;       // 1,048,576
    float* xg      = ws + 2097152;       // 4,194,304
    float* hp      = ws + 6291456;       // 1,048,576
    float* partial = ws + 7340032;       // 512

    hipLaunchKernelGGL(k_transpose_wv, dim3(V_/16), dim3(256), 0, stream, Wv, WT);
    hipLaunchKernelGGL(k_visit_embed, dim3(NROW), dim3(256), 0, stream, px, vmask, bins, bemb, WT, v);
    hipLaunchKernelGGL(k_gemm_xg, dim3(NROW/16), dim3(256), 0, stream, v, Wih, bih, bhh, xg);
    hipLaunchKernelGGL(k_lstm_fused, dim3(B_/16), dim3(512), 0, stream,
                       xg, Whh, Wproj, Wcls, bcls, vmask, hp, out);
    hipLaunchKernelGGL(k_drg, dim3(NROW/16), dim3(256), 0, stream,
                       v, hp, eps, tdiff, vmask, z0, noise, temb, Wf, bfu,
                       We1, be1, We2, be2, Wih, bih, bhh, partial, xg);
    hipLaunchKernelGGL(k_lstm_fused, dim3(B_/16), dim3(512), 0, stream,
                       xg, Whh, Wproj, Wcls, bcls, vmask, (float*)nullptr, out + 128);
    hipLaunchKernelGGL(k_finalize, dim3(1), dim3(256), 0, stream, partial, vmask, out);
}